// Round 1
// baseline (1729.659 us; speedup 1.0000x reference)
//
#include <hip/hip_runtime.h>
#include <math.h>

#define NB 8
#define NH 12
#define SEQ 784
#define CH 768
#define DH 64
#define K_TOP 100

typedef long long i64;

// C[i,j] = alpha * sum_k A[i*lda+k] * B[j*ldb+k]  (+ bias[j])
// batched via blockIdx.z with element strides sA/sB/sC.
__global__ __launch_bounds__(256)
void gemm_nt(const float* __restrict__ A, const float* __restrict__ B,
             float* __restrict__ C, const float* __restrict__ bias,
             int M, int N, int K, int lda, int ldb, int ldc,
             i64 sA, i64 sB, i64 sC, float alpha)
{
    __shared__ __align__(16) float As[8][128];
    __shared__ __align__(16) float Bs[8][128];
    const int tid = threadIdx.x;
    const int tx = tid & 15, ty = tid >> 4;
    const int m0 = blockIdx.y * 128, n0 = blockIdx.x * 128;
    A += (i64)blockIdx.z * sA;
    B += (i64)blockIdx.z * sB;
    C += (i64)blockIdx.z * sC;

    // loader: 2 threads per row, each loads a float4 along K
    const int lr = tid >> 1;          // 0..127: tile row
    const int lk = (tid & 1) << 2;    // 0 or 4
    const int arow = m0 + lr;
    const int brow = n0 + lr;
    const bool aval = arow < M;
    const bool bval = brow < N;
    const float* Ap = A + (i64)arow * lda + lk;
    const float* Bp = B + (i64)brow * ldb + lk;

    float acc[8][8];
#pragma unroll
    for (int i = 0; i < 8; i++)
#pragma unroll
        for (int j = 0; j < 8; j++) acc[i][j] = 0.0f;

    for (int k0 = 0; k0 < K; k0 += 8) {
        float4 av = make_float4(0.f,0.f,0.f,0.f);
        float4 bv = make_float4(0.f,0.f,0.f,0.f);
        if (aval) av = *(const float4*)(Ap + k0);
        if (bval) bv = *(const float4*)(Bp + k0);
        __syncthreads();   // previous iteration's readers done
        As[lk+0][lr] = av.x; As[lk+1][lr] = av.y; As[lk+2][lr] = av.z; As[lk+3][lr] = av.w;
        Bs[lk+0][lr] = bv.x; Bs[lk+1][lr] = bv.y; Bs[lk+2][lr] = bv.z; Bs[lk+3][lr] = bv.w;
        __syncthreads();
#pragma unroll
        for (int kk = 0; kk < 8; kk++) {
            float4 a0 = *(const float4*)&As[kk][ty*8];
            float4 a1 = *(const float4*)&As[kk][ty*8+4];
            float4 b0 = *(const float4*)&Bs[kk][tx*8];
            float4 b1 = *(const float4*)&Bs[kk][tx*8+4];
            float a[8]  = {a0.x,a0.y,a0.z,a0.w,a1.x,a1.y,a1.z,a1.w};
            float bb[8] = {b0.x,b0.y,b0.z,b0.w,b1.x,b1.y,b1.z,b1.w};
#pragma unroll
            for (int i = 0; i < 8; i++)
#pragma unroll
                for (int j = 0; j < 8; j++)
                    acc[i][j] = fmaf(a[i], bb[j], acc[i][j]);
        }
    }

#pragma unroll
    for (int i = 0; i < 8; i++) {
        int row = m0 + ty*8 + i;
        if (row >= M) continue;
#pragma unroll
        for (int j = 0; j < 8; j++) {
            int col = n0 + tx*8 + j;
            if (col >= N) continue;
            float v = alpha * acc[i][j];
            if (bias) v += bias[col];
            C[(i64)row * ldc + col] = v;
        }
    }
}

// One block per (h, n) row for a fixed batch b.
// scores: [H][SEQ][SEQ] for this b (pre-scaled by 0.125).
// Finds exact top-100 of scores+ucb (stable ties by lowest index),
// writes context row into ctx (B,N,C layout) and accumulates score_delta.
__global__ __launch_bounds__(256)
void select_topk(const float* __restrict__ scores,
                 const float* __restrict__ ucb_cnt,
                 const float* __restrict__ qkv,
                 float* __restrict__ ctx,
                 float* __restrict__ sdelta,
                 const int* __restrict__ counter_p,
                 int b)
{
    __shared__ float    s_vals[SEQ];
    __shared__ unsigned u_vals[SEQ];
    __shared__ unsigned char selflag[SEQ];
    __shared__ unsigned hist[256];
    __shared__ float    cred[256];
    __shared__ float    wsel[128];
    __shared__ int      isel[128];
    __shared__ unsigned sh_prefix;
    __shared__ int      sh_r, sh_cnt;
    __shared__ float    sh_inv;

    const int tid = threadIdx.x;
    const int n = blockIdx.x, h = blockIdx.y;
    const float L = logf((float)(*counter_p));   // counter=1000 > 500, ucb path

    const i64 rowoff = ((i64)h * SEQ + n) * SEQ;

    for (int m = tid; m < SEQ; m += 256) {
        float s = scores[rowoff + m];
        float c = ucb_cnt[rowoff + m];
        float t = s + sqrtf(L / (c + 1e-6f));
        unsigned bits = __float_as_uint(t);
        unsigned u = (bits & 0x80000000u) ? ~bits : (bits | 0x80000000u);
        s_vals[m] = s; u_vals[m] = u; selflag[m] = 0;
    }
    if (tid == 0) { sh_prefix = 0u; sh_r = K_TOP; sh_cnt = 0; }
    __syncthreads();

    // 4-pass MSB radix select: find bit pattern T of the 100th-largest
    for (int pass = 3; pass >= 0; pass--) {
        const int shift = pass * 8;
        const unsigned prefix = sh_prefix;
        const int r = sh_r;
        const unsigned mask_hi = (pass == 3) ? 0u : (0xFFFFFFFFu << (shift + 8));
        hist[tid] = 0u;
        __syncthreads();
        for (int m = tid; m < SEQ; m += 256) {
            unsigned u = u_vals[m];
            if ((u & mask_hi) == prefix)
                atomicAdd(&hist[(u >> shift) & 255u], 1u);
        }
        __syncthreads();
        // inclusive suffix scan: hist[d] = count of candidates with digit >= d
#pragma unroll
        for (int off = 1; off < 256; off <<= 1) {
            unsigned v = hist[tid];
            unsigned w = (tid + off < 256) ? hist[tid + off] : 0u;
            __syncthreads();
            hist[tid] = v + w;
            __syncthreads();
        }
        unsigned cge = hist[tid];
        unsigned cgt = (tid < 255) ? hist[tid + 1] : 0u;
        if ((int)cge >= r && (int)cgt < r) {
            sh_prefix = prefix | ((unsigned)tid << shift);
            sh_r = r - (int)cgt;
        }
        __syncthreads();
    }
    const unsigned T = sh_prefix;
    const int rfin = sh_r;    // how many ==T elements to take (by lowest index)

    // mark u > T; count equals
    float peq = 0.f;
    for (int m = tid; m < SEQ; m += 256) {
        unsigned u = u_vals[m];
        if (u > T) selflag[m] = 1;
        if (u == T) peq += 1.0f;
    }
    cred[tid] = peq; __syncthreads();
    for (int s = 128; s > 0; s >>= 1) { if (tid < s) cred[tid] += cred[tid + s]; __syncthreads(); }
    const int ceq = (int)cred[0];
    __syncthreads();
    if (ceq == rfin) {
        for (int m = tid; m < SEQ; m += 256)
            if (u_vals[m] == T) selflag[m] = 1;
    } else if (tid == 0) {
        int nd = rfin;
        for (int m = 0; m < SEQ && nd > 0; m++)
            if (u_vals[m] == T) { selflag[m] = 1; nd--; }
    }
    __syncthreads();

    // compact selected + weight sum (weights are the raw scaled scores)
    float pw = 0.f;
    for (int m = tid; m < SEQ; m += 256) {
        if (selflag[m]) {
            int pos = atomicAdd(&sh_cnt, 1);
            if (pos < 128) { isel[pos] = m; wsel[pos] = s_vals[m]; }
            pw += s_vals[m];
        }
    }
    cred[tid] = pw; __syncthreads();
    for (int s = 128; s > 0; s >>= 1) { if (tid < s) cred[tid] += cred[tid + s]; __syncthreads(); }
    if (tid == 0) sh_inv = 1.0f / (cred[0] + 1e-8f);
    __syncthreads();
    const float inv = sh_inv;
    const int cnt = (sh_cnt < 128) ? sh_cnt : 128;

    // context: ctx[b,n,h*64+d] = inv * sum_j w_j * v[b,h,idx_j,d]
    const int d = tid & 63, g = tid >> 6;
    float acc = 0.f;
    const float* vbase = qkv + ((i64)b * SEQ) * (3*CH) + 2*CH + h * DH + d;
    for (int j = g; j < cnt; j += 4)
        acc += wsel[j] * vbase[(i64)isel[j] * (3*CH)];
    cred[tid] = acc; __syncthreads();
    if (tid < 64) {
        float tot = cred[tid] + cred[tid+64] + cred[tid+128] + cred[tid+192];
        ctx[((i64)b * SEQ + n) * CH + h * DH + tid] = inv * tot;
    }

    // score_delta accumulation (b sequential launches -> no atomics needed)
    for (int m = tid; m < SEQ; m += 256) {
        float f = selflag[m] ? 1.0f : 0.0f;
        if (b == 0) sdelta[rowoff + m] = f;
        else        sdelta[rowoff + m] += f;
    }
}

extern "C" void kernel_launch(void* const* d_in, const int* in_sizes, int n_in,
                              void* d_out, int out_size, void* d_ws, size_t ws_size,
                              hipStream_t stream) {
    const float* x      = (const float*)d_in[0];   // (8,784,768)
    const float* ucb    = (const float*)d_in[1];   // (12,784,784)
    const float* qkv_w  = (const float*)d_in[2];   // (2304,768)
    const float* proj_w = (const float*)d_in[3];   // (768,768)
    const float* proj_b = (const float*)d_in[4];   // (768,)
    const int*   counter = (const int*)d_in[5];    // 1000 -> ucb branch taken

    float* out0   = (float*)d_out;                         // (8,784,768)
    float* sdelta = out0 + (i64)NB * SEQ * CH;             // (12,784,784)

    float* qkv_buf = (float*)d_ws;                         // 6272 x 2304
    float* ctx     = qkv_buf + (i64)NB * SEQ * (3*CH);     // 6272 x 768
    float* scores  = ctx + (i64)NB * SEQ * CH;             // 12 x 784 x 784 (per-b reuse)

    dim3 blk(256);

    // qkv = x @ qkv_w.T   (M=6272, N=2304, K=768)
    gemm_nt<<<dim3(2304/128, 6272/128, 1), blk, 0, stream>>>(
        x, qkv_w, qkv_buf, nullptr,
        NB*SEQ, 3*CH, CH, CH, CH, 3*CH, 0, 0, 0, 1.0f);

    for (int b = 0; b < NB; b++) {
        const float* qb = qkv_buf + (i64)b * SEQ * (3*CH);
        // scores[h] = 0.125 * q_bh @ k_bh^T   (batched over h via z, stride 64)
        gemm_nt<<<dim3(7, 7, NH), blk, 0, stream>>>(
            qb, qb + CH, scores, nullptr,
            SEQ, SEQ, DH, 3*CH, 3*CH, SEQ,
            (i64)DH, (i64)DH, (i64)SEQ*SEQ, 0.125f);

        select_topk<<<dim3(SEQ, NH), blk, 0, stream>>>(
            scores, ucb, qkv_buf, ctx, sdelta, counter, b);
    }

    // out = ctx @ proj_w.T + proj_b   (M=6272, N=768, K=768)
    gemm_nt<<<dim3(768/128, 6272/128, 1), blk, 0, stream>>>(
        ctx, proj_w, out0, proj_b,
        NB*SEQ, CH, CH, CH, CH, CH, 0, 0, 0, 1.0f);
}

// Round 2
// 1382.029 us; speedup vs baseline: 1.2515x; 1.2515x over previous
//
#include <hip/hip_runtime.h>
#include <math.h>

#define NB 8
#define NH 12
#define SEQ 784
#define CH 768
#define DH 64
#define K_TOP 100
#define NE4 196   // SEQ/4

typedef long long i64;

// C[i,j] = alpha * sum_k A[i*lda+k] * B[j*ldb+k]  (+ bias[j])
// z decomposed: zb = z/zdiv, zh = z%zdiv; base += zb*s?1 + zh*s?2
__global__ __launch_bounds__(256)
void gemm_nt(const float* __restrict__ A, const float* __restrict__ B,
             float* __restrict__ C, const float* __restrict__ bias,
             int M, int N, int K, int lda, int ldb, int ldc,
             int zdiv, i64 sA1, i64 sA2, i64 sB1, i64 sB2, i64 sC1, i64 sC2,
             float alpha)
{
    __shared__ __align__(16) float As[8][128];
    __shared__ __align__(16) float Bs[8][128];
    const int tid = threadIdx.x;
    const int tx = tid & 15, ty = tid >> 4;
    const int m0 = blockIdx.y * 128, n0 = blockIdx.x * 128;
    const int zb = blockIdx.z / zdiv, zh = blockIdx.z % zdiv;
    A += zb * sA1 + zh * sA2;
    B += zb * sB1 + zh * sB2;
    C += zb * sC1 + zh * sC2;

    // loader: 2 threads per tile-row, each a float4 along K
    const int lr = tid >> 1;
    const int lk = (tid & 1) << 2;
    const bool aval = (m0 + lr) < M;
    const bool bval = (n0 + lr) < N;
    const float* Ap = A + (i64)(m0 + lr) * lda + lk;
    const float* Bp = B + (i64)(n0 + lr) * ldb + lk;

    float4 av = make_float4(0.f,0.f,0.f,0.f), bv = av;
    if (aval) av = *(const float4*)(Ap);
    if (bval) bv = *(const float4*)(Bp);

    float acc[8][8];
#pragma unroll
    for (int i = 0; i < 8; i++)
#pragma unroll
        for (int j = 0; j < 8; j++) acc[i][j] = 0.0f;

    for (int k0 = 0; k0 < K; k0 += 8) {
        __syncthreads();   // previous iteration's readers done
        As[lk+0][lr] = av.x; As[lk+1][lr] = av.y; As[lk+2][lr] = av.z; As[lk+3][lr] = av.w;
        Bs[lk+0][lr] = bv.x; Bs[lk+1][lr] = bv.y; Bs[lk+2][lr] = bv.z; Bs[lk+3][lr] = bv.w;
        __syncthreads();
        if (k0 + 8 < K) {   // prefetch next tile BEFORE compute (hide VMEM latency)
            if (aval) av = *(const float4*)(Ap + k0 + 8);
            if (bval) bv = *(const float4*)(Bp + k0 + 8);
        }
#pragma unroll
        for (int kk = 0; kk < 8; kk++) {
            // 2x2 blocks of 4x4: stride-4 addresses -> 2-way LDS aliasing only (free)
            float4 a0 = *(const float4*)&As[kk][ty*4];
            float4 a1 = *(const float4*)&As[kk][64 + ty*4];
            float4 b0 = *(const float4*)&Bs[kk][tx*4];
            float4 b1 = *(const float4*)&Bs[kk][64 + tx*4];
            float a[8]  = {a0.x,a0.y,a0.z,a0.w,a1.x,a1.y,a1.z,a1.w};
            float bb[8] = {b0.x,b0.y,b0.z,b0.w,b1.x,b1.y,b1.z,b1.w};
#pragma unroll
            for (int i = 0; i < 8; i++)
#pragma unroll
                for (int j = 0; j < 8; j++)
                    acc[i][j] = fmaf(a[i], bb[j], acc[i][j]);
        }
    }

#pragma unroll
    for (int i = 0; i < 8; i++) {
        const int row = m0 + ty*4 + (i & 3) + ((i >> 2) * 64);
        if (row >= M) continue;
#pragma unroll
        for (int jg = 0; jg < 2; jg++) {
            const int col = n0 + jg*64 + tx*4;
            if (col >= N) continue;   // N%4==0 and groups 4-aligned -> all-or-nothing
            float4 o;
            o.x = alpha * acc[i][jg*4+0];
            o.y = alpha * acc[i][jg*4+1];
            o.z = alpha * acc[i][jg*4+2];
            o.w = alpha * acc[i][jg*4+3];
            if (bias) {
                float4 b4 = *(const float4*)&bias[col];
                o.x += b4.x; o.y += b4.y; o.z += b4.z; o.w += b4.w;
            }
            *(float4*)&C[(i64)row * ldc + col] = o;
        }
    }
}

__device__ __forceinline__ float wave_fsum(float v) {
#pragma unroll
    for (int m = 32; m; m >>= 1) v += __shfl_xor(v, m, 64);
    return v;
}
__device__ __forceinline__ int wave_isum(int v) {
#pragma unroll
    for (int m = 32; m; m >>= 1) v += __shfl_xor(v, m, 64);
    return v;
}
__device__ __forceinline__ unsigned fkey(float t) {
    unsigned bits = __float_as_uint(t);
    return (bits & 0x80000000u) ? ~bits : (bits | 0x80000000u);
}

// One block per (h,n); loops b in [b0,b1). scores row for b at
// scores + (b-b0)*sstride + (h*SEQ+n)*SEQ (pre-scaled by 0.125).
__global__ __launch_bounds__(256)
void select_topk(const float* __restrict__ scores, i64 sstride,
                 const float* __restrict__ ucb_cnt,
                 const float* __restrict__ qkv,
                 float* __restrict__ ctx,
                 float* __restrict__ sdelta,
                 const int* __restrict__ counter_p,
                 int b0, int b1)
{
    __shared__ __align__(16) float    s_vals[SEQ];
    __shared__ __align__(16) unsigned u_vals[SEQ];
    __shared__ __align__(4)  unsigned char selflag[SEQ];
    __shared__ unsigned hist[256];
    __shared__ unsigned wtot[4];
    __shared__ float    fred[4];
    __shared__ int      ired[4];
    __shared__ float    cred[256];
    __shared__ float    wsel[128];
    __shared__ int      isel[128];
    __shared__ unsigned sh_prefix;
    __shared__ int      sh_r, sh_cnt;

    const int tid = threadIdx.x;
    const int lane = tid & 63, wid = tid >> 6;
    const int n = blockIdx.x, h = blockIdx.y;
    const float L = logf((float)(*counter_p));   // counter=1000>500 -> ucb path
    const i64 rowoff = ((i64)h * SEQ + n) * SEQ;
    const bool owner = tid < NE4;

    // ucb bonus: shared across b -> compute once per block
    float4 bon = make_float4(0.f,0.f,0.f,0.f);
    if (owner) {
        float4 c4 = *(const float4*)&ucb_cnt[rowoff + tid*4];
        bon.x = sqrtf(L / (c4.x + 1e-6f));
        bon.y = sqrtf(L / (c4.y + 1e-6f));
        bon.z = sqrtf(L / (c4.z + 1e-6f));
        bon.w = sqrtf(L / (c4.w + 1e-6f));
    }
    int cnt_acc[4] = {0,0,0,0};
    hist[tid] = 0u;

    for (int b = b0; b < b1; b++) {
        const float* srow = scores + (i64)(b - b0) * sstride + rowoff;
        if (tid == 0) { sh_prefix = 0u; sh_r = K_TOP; sh_cnt = 0; }
        if (owner) {
            float4 s4 = *(const float4*)&srow[tid*4];
            *(float4*)&s_vals[tid*4] = s4;
            uint4 uu;
            uu.x = fkey(s4.x + bon.x);
            uu.y = fkey(s4.y + bon.y);
            uu.z = fkey(s4.z + bon.z);
            uu.w = fkey(s4.w + bon.w);
            *(uint4*)&u_vals[tid*4] = uu;
            *(uchar4*)&selflag[tid*4] = make_uchar4(0,0,0,0);
        }
        __syncthreads();

        // 4-pass MSB radix select: bit pattern T of the 100th-largest
        unsigned prefix = 0u; int r = K_TOP;
#pragma unroll
        for (int pass = 3; pass >= 0; pass--) {
            const int shift = pass * 8;
            const unsigned mask_hi = (pass == 3) ? 0u : (0xFFFFFFFFu << (shift + 8));
            if (owner) {
#pragma unroll
                for (int j = 0; j < 4; j++) {
                    unsigned u = u_vals[tid*4 + j];
                    if ((u & mask_hi) == prefix)
                        atomicAdd(&hist[(u >> shift) & 255u], 1u);
                }
            }
            __syncthreads();
            const unsigned hme = hist[tid];
            unsigned ssum = hme;          // wave-level inclusive suffix scan
#pragma unroll
            for (int off = 1; off < 64; off <<= 1) {
                unsigned t = __shfl_down(ssum, off, 64);
                if (lane + off < 64) ssum += t;
            }
            if (lane == 0) wtot[wid] = ssum;
            __syncthreads();
            unsigned above = 0;
            for (int w = wid + 1; w < 4; w++) above += wtot[w];
            const unsigned cge = ssum + above;     // count of candidates >= this digit
            const unsigned cgt = cge - hme;        // count strictly greater
            if ((int)cge >= r && (int)cgt < r) {
                sh_prefix = prefix | ((unsigned)tid << shift);
                sh_r = r - (int)cgt;
            }
            hist[tid] = 0u;   // ready for next pass
            __syncthreads();
            prefix = sh_prefix; r = sh_r;
        }
        const unsigned T = prefix;
        const int rfin = r;

        // flags: u > T always in; count equals
        int myeq = 0;
        if (owner) {
#pragma unroll
            for (int j = 0; j < 4; j++) {
                unsigned u = u_vals[tid*4 + j];
                if (u > T) selflag[tid*4 + j] = 1;
                myeq += (u == T);
            }
        }
        int weq = wave_isum(myeq);
        if (lane == 0) ired[wid] = weq;
        __syncthreads();
        const int ceq = ired[0] + ired[1] + ired[2] + ired[3];
        if (ceq == rfin) {
            if (owner) {
#pragma unroll
                for (int j = 0; j < 4; j++)
                    if (u_vals[tid*4 + j] == T) selflag[tid*4 + j] = 1;
            }
        } else if (tid == 0) {   // rare exact-duplicate tie: stable by lowest index
            int nd = rfin;
            for (int m = 0; m < SEQ && nd > 0; m++)
                if (u_vals[m] == T) { selflag[m] = 1; nd--; }
        }
        __syncthreads();

        // compact + per-elem count accumulate + weight sum
        float pw = 0.f;
        if (owner) {
#pragma unroll
            for (int j = 0; j < 4; j++) {
                if (selflag[tid*4 + j]) {
                    int pos = atomicAdd(&sh_cnt, 1);
                    if (pos < 128) { isel[pos] = tid*4 + j; wsel[pos] = s_vals[tid*4 + j]; }
                    pw += s_vals[tid*4 + j];
                    cnt_acc[j]++;
                }
            }
        }
        float w0 = wave_fsum(pw);
        if (lane == 0) fred[wid] = w0;
        __syncthreads();
        const float inv = 1.0f / (fred[0] + fred[1] + fred[2] + fred[3] + 1e-8f);
        const int cnt = (sh_cnt < 128) ? sh_cnt : 128;

        // context row: ctx[b,n,h*64+d] = inv * sum_j w_j * v[b,h,idx_j,d]
        const int d = tid & 63, g = tid >> 6;
        float acc = 0.f;
        const float* vbase = qkv + (i64)b * SEQ * (3*CH) + 2*CH + h * DH + d;
        for (int j = g; j < cnt; j += 4)
            acc += wsel[j] * vbase[(i64)isel[j] * (3*CH)];
        cred[tid] = acc;
        __syncthreads();
        if (tid < 64) {
            float tot = cred[tid] + cred[tid+64] + cred[tid+128] + cred[tid+192];
            ctx[((i64)b * SEQ + n) * CH + h * DH + tid] = inv * tot;
        }
        __syncthreads();   // cred/selflag/s_vals reused next b
    }

    // score_delta: counts accumulated in regs across processed b's
    if (owner) {
        float4 o;
        o.x = (float)cnt_acc[0]; o.y = (float)cnt_acc[1];
        o.z = (float)cnt_acc[2]; o.w = (float)cnt_acc[3];
        float* dst = &sdelta[rowoff + tid*4];
        if (b0 == 0 && b1 == NB) {
            *(float4*)dst = o;
        } else if (b0 == 0) {
            *(float4*)dst = o;
        } else {
            float4 p = *(const float4*)dst;
            o.x += p.x; o.y += p.y; o.z += p.z; o.w += p.w;
            *(float4*)dst = o;
        }
    }
}

extern "C" void kernel_launch(void* const* d_in, const int* in_sizes, int n_in,
                              void* d_out, int out_size, void* d_ws, size_t ws_size,
                              hipStream_t stream) {
    const float* x      = (const float*)d_in[0];   // (8,784,768)
    const float* ucb    = (const float*)d_in[1];   // (12,784,784)
    const float* qkv_w  = (const float*)d_in[2];   // (2304,768)
    const float* proj_w = (const float*)d_in[3];   // (768,768)
    const float* proj_b = (const float*)d_in[4];   // (768,)
    const int*   counter = (const int*)d_in[5];    // 1000 -> ucb branch

    float* out0   = (float*)d_out;                         // (8,784,768)
    float* sdelta = out0 + (i64)NB * SEQ * CH;             // (12,784,784)

    const size_t qkv_f = (size_t)NB * SEQ * (3*CH);
    const size_t ctx_f = (size_t)NB * SEQ * CH;
    const size_t sc1_f = (size_t)NH * SEQ * SEQ;
    float* qkv_buf = (float*)d_ws;
    float* ctx     = qkv_buf + qkv_f;
    float* scores  = ctx + ctx_f;
    const bool merged = ws_size >= (qkv_f + ctx_f + (size_t)NB * sc1_f) * sizeof(float);

    dim3 blk(256);

    // qkv = x @ qkv_w.T   (M=6272, N=2304, K=768)
    gemm_nt<<<dim3(2304/128, 6272/128, 1), blk, 0, stream>>>(
        x, qkv_w, qkv_buf, nullptr,
        NB*SEQ, 3*CH, CH, CH, CH, 3*CH,
        1, 0, 0, 0, 0, 0, 0, 1.0f);

    if (merged) {
        // scores[b,h] = 0.125 * q_bh @ k_bh^T for ALL b,h in one launch (z = b*NH+h)
        gemm_nt<<<dim3(7, 7, NB*NH), blk, 0, stream>>>(
            qkv_buf, qkv_buf + CH, scores, nullptr,
            SEQ, SEQ, DH, 3*CH, 3*CH, SEQ,
            NH, (i64)SEQ*(3*CH), (i64)DH, (i64)SEQ*(3*CH), (i64)DH,
            (i64)NH*SEQ*SEQ, (i64)SEQ*SEQ, 0.125f);
        select_topk<<<dim3(SEQ, NH), blk, 0, stream>>>(
            scores, (i64)NH*SEQ*SEQ, ucb, qkv_buf, ctx, sdelta, counter, 0, NB);
    } else {
        for (int b = 0; b < NB; b++) {
            const float* qb = qkv_buf + (i64)b * SEQ * (3*CH);
            gemm_nt<<<dim3(7, 7, NH), blk, 0, stream>>>(
                qb, qb + CH, scores, nullptr,
                SEQ, SEQ, DH, 3*CH, 3*CH, SEQ,
                1, (i64)DH, 0, (i64)DH, 0, (i64)SEQ*SEQ, 0, 0.125f);
            select_topk<<<dim3(SEQ, NH), blk, 0, stream>>>(
                scores, 0, ucb, qkv_buf, ctx, sdelta, counter, b, b + 1);
        }
    }

    // out = ctx @ proj_w.T + proj_b   (M=6272, N=768, K=768)
    gemm_nt<<<dim3(768/128, 6272/128, 1), blk, 0, stream>>>(
        ctx, proj_w, out0, proj_b,
        NB*SEQ, CH, CH, CH, CH, CH,
        1, 0, 0, 0, 0, 0, 0, 1.0f);
}

// Round 3
// 1231.794 us; speedup vs baseline: 1.4042x; 1.1220x over previous
//
#include <hip/hip_runtime.h>
#include <hip/hip_bf16.h>
#include <math.h>

#define NB 8
#define NH 12
#define SEQ 784
#define CH 768
#define DH 64
#define K_TOP 100
#define NE4 196   // SEQ/4

typedef long long i64;
typedef __attribute__((ext_vector_type(8))) short bf16x8;
typedef __attribute__((ext_vector_type(4))) float f32x4;

// ---------------- QKV GEMM: C = A @ B^T, fp32 vector, BK=16 ----------------
// M=6272, N=2304, K=768 (all exact multiples -> no guards).
__global__ __launch_bounds__(256)
void gemm_qkv(const float* __restrict__ A, const float* __restrict__ B,
              float* __restrict__ C)
{
    __shared__ __align__(16) float As[16][128];
    __shared__ __align__(16) float Bs[16][128];
    const int tid = threadIdx.x;
    const int tx = tid & 15, ty = tid >> 4;
    const int m0 = blockIdx.y * 128, n0 = blockIdx.x * 128;

    const int r  = tid >> 2;          // 0..63
    const int kc = (tid & 3) << 2;    // 0,4,8,12
    const float* ApL = A + (i64)(m0 + r)      * CH + kc;
    const float* ApH = A + (i64)(m0 + r + 64) * CH + kc;
    const float* BpL = B + (i64)(n0 + r)      * CH + kc;
    const float* BpH = B + (i64)(n0 + r + 64) * CH + kc;

    float4 a0 = *(const float4*)ApL, a1 = *(const float4*)ApH;
    float4 b0 = *(const float4*)BpL, b1 = *(const float4*)BpH;

    float acc[8][8];
#pragma unroll
    for (int i = 0; i < 8; i++)
#pragma unroll
        for (int j = 0; j < 8; j++) acc[i][j] = 0.0f;

    for (int k0 = 0; k0 < CH; k0 += 16) {
        __syncthreads();
#pragma unroll
        for (int j = 0; j < 4; j++) {
            As[kc+j][r]    = ((const float*)&a0)[j];
            As[kc+j][r+64] = ((const float*)&a1)[j];
            Bs[kc+j][r]    = ((const float*)&b0)[j];
            Bs[kc+j][r+64] = ((const float*)&b1)[j];
        }
        __syncthreads();
        if (k0 + 16 < CH) {
            a0 = *(const float4*)(ApL + k0 + 16);
            a1 = *(const float4*)(ApH + k0 + 16);
            b0 = *(const float4*)(BpL + k0 + 16);
            b1 = *(const float4*)(BpH + k0 + 16);
        }
#pragma unroll
        for (int kk = 0; kk < 16; kk++) {
            float4 x0 = *(const float4*)&As[kk][ty*4];
            float4 x1 = *(const float4*)&As[kk][64 + ty*4];
            float4 y0 = *(const float4*)&Bs[kk][tx*4];
            float4 y1 = *(const float4*)&Bs[kk][64 + tx*4];
            float a[8]  = {x0.x,x0.y,x0.z,x0.w,x1.x,x1.y,x1.z,x1.w};
            float bb[8] = {y0.x,y0.y,y0.z,y0.w,y1.x,y1.y,y1.z,y1.w};
#pragma unroll
            for (int i = 0; i < 8; i++)
#pragma unroll
                for (int j = 0; j < 8; j++)
                    acc[i][j] = fmaf(a[i], bb[j], acc[i][j]);
        }
    }

#pragma unroll
    for (int i = 0; i < 8; i++) {
        const int row = m0 + ty*4 + (i & 3) + ((i >> 2) * 64);
#pragma unroll
        for (int jg = 0; jg < 2; jg++) {
            const int col = n0 + jg*64 + tx*4;
            float4 o = make_float4(acc[i][jg*4+0], acc[i][jg*4+1],
                                   acc[i][jg*4+2], acc[i][jg*4+3]);
            *(float4*)&C[(i64)row * (3*CH) + col] = o;
        }
    }
}

// ---------------- scores GEMM: one-shot BK=64 (K=DH) -----------------------
// scores[z] = 0.125 * q_z @ k_z^T, z = (b_base + zz/NH)*NH + zz%NH
__global__ __launch_bounds__(256)
void gemm_scores(const float* __restrict__ qkv, float* __restrict__ scores,
                 int b_base, i64 sC)
{
    __shared__ __align__(16) float As[64][128];
    __shared__ __align__(16) float Bs[64][128];
    const int tid = threadIdx.x;
    const int tx = tid & 15, ty = tid >> 4;
    const int m0 = blockIdx.y * 128, n0 = blockIdx.x * 128;
    const int b = b_base + blockIdx.z / NH, h = blockIdx.z % NH;

    const float* A = qkv + (i64)b * SEQ * (3*CH) + h * DH;   // q rows
    const float* B = A + CH;                                  // k rows
    float* C = scores + (i64)blockIdx.z * sC;

    // loader: 4 threads/row, each 4 consecutive float4 (64B)
    const int lrow = tid >> 2;
    const int lk = (tid & 3) * 16;   // float offset base
    {
        float4 av[2][4], bv[2][4];
#pragma unroll
        for (int g = 0; g < 2; g++) {
            int ar = m0 + g*64 + lrow; if (ar > SEQ-1) ar = SEQ-1;
            int br = n0 + g*64 + lrow; if (br > SEQ-1) br = SEQ-1;
            const float* Ap = A + (i64)ar * (3*CH) + lk;
            const float* Bp = B + (i64)br * (3*CH) + lk;
#pragma unroll
            for (int c = 0; c < 4; c++) {
                av[g][c] = *(const float4*)(Ap + c*4);
                bv[g][c] = *(const float4*)(Bp + c*4);
            }
        }
#pragma unroll
        for (int g = 0; g < 2; g++)
#pragma unroll
            for (int c = 0; c < 4; c++)
#pragma unroll
                for (int j = 0; j < 4; j++) {
                    As[lk + c*4 + j][g*64 + lrow] = ((const float*)&av[g][c])[j];
                    Bs[lk + c*4 + j][g*64 + lrow] = ((const float*)&bv[g][c])[j];
                }
    }
    __syncthreads();

    float acc[8][8];
#pragma unroll
    for (int i = 0; i < 8; i++)
#pragma unroll
        for (int j = 0; j < 8; j++) acc[i][j] = 0.0f;

#pragma unroll 8
    for (int kk = 0; kk < 64; kk++) {
        float4 x0 = *(const float4*)&As[kk][ty*4];
        float4 x1 = *(const float4*)&As[kk][64 + ty*4];
        float4 y0 = *(const float4*)&Bs[kk][tx*4];
        float4 y1 = *(const float4*)&Bs[kk][64 + tx*4];
        float a[8]  = {x0.x,x0.y,x0.z,x0.w,x1.x,x1.y,x1.z,x1.w};
        float bb[8] = {y0.x,y0.y,y0.z,y0.w,y1.x,y1.y,y1.z,y1.w};
#pragma unroll
        for (int i = 0; i < 8; i++)
#pragma unroll
            for (int j = 0; j < 8; j++)
                acc[i][j] = fmaf(a[i], bb[j], acc[i][j]);
    }

#pragma unroll
    for (int i = 0; i < 8; i++) {
        const int row = m0 + ty*4 + (i & 3) + ((i >> 2) * 64);
        if (row >= SEQ) continue;
#pragma unroll
        for (int jg = 0; jg < 2; jg++) {
            const int col = n0 + jg*64 + tx*4;
            if (col >= SEQ) continue;   // SEQ%4==0 -> all-or-nothing
            float4 o = make_float4(0.125f*acc[i][jg*4+0], 0.125f*acc[i][jg*4+1],
                                   0.125f*acc[i][jg*4+2], 0.125f*acc[i][jg*4+3]);
            *(float4*)&C[(i64)row * SEQ + col] = o;
        }
    }
}

// ---------------- proj: out = ctx_bf @ projw_bf^T + bias, bf16 MFMA --------
// M=6272, N=768, K=768 (exact multiples). LDS rows padded to 40 bf16 (80B).
__global__ __launch_bounds__(256)
void gemm_proj(const unsigned short* __restrict__ Abf,
               const unsigned short* __restrict__ Bbf,
               const float* __restrict__ bias, float* __restrict__ C)
{
    __shared__ __align__(16) unsigned short As[128 * 40];
    __shared__ __align__(16) unsigned short Bs[128 * 40];
    const int tid = threadIdx.x;
    const int lane = tid & 63, w = tid >> 6;
    const int wm = (w >> 1) * 64, wn = (w & 1) * 64;
    const int m0 = blockIdx.y * 128, n0 = blockIdx.x * 128;

    f32x4 acc[4][4];
#pragma unroll
    for (int i = 0; i < 4; i++)
#pragma unroll
        for (int j = 0; j < 4; j++) acc[i][j] = (f32x4){0.f,0.f,0.f,0.f};

    const int q = lane >> 4;          // k-quad 0..3
    const int rA = lane & 15;

    for (int k0 = 0; k0 < CH; k0 += 32) {
        __syncthreads();
        // stage 128x32 bf16 of A and B
#pragma unroll
        for (int rep = 0; rep < 2; rep++) {
            const int id = rep * 256 + tid;
            const int row = id >> 2, c = id & 3;
            *(uint4*)&As[row*40 + c*8] = *(const uint4*)&Abf[(i64)(m0+row)*CH + k0 + c*8];
            *(uint4*)&Bs[row*40 + c*8] = *(const uint4*)&Bbf[(i64)(n0+row)*CH + k0 + c*8];
        }
        __syncthreads();
#pragma unroll
        for (int mt = 0; mt < 4; mt++) {
            bf16x8 a = *(const bf16x8*)&As[(wm + mt*16 + rA)*40 + q*8];
#pragma unroll
            for (int nt = 0; nt < 4; nt++) {
                bf16x8 b = *(const bf16x8*)&Bs[(wn + nt*16 + rA)*40 + q*8];
                acc[mt][nt] = __builtin_amdgcn_mfma_f32_16x16x32_bf16(a, b, acc[mt][nt], 0, 0, 0);
            }
        }
    }

    // C/D layout: col = lane&15, row = (lane>>4)*4 + reg  [m89-verified]
#pragma unroll
    for (int mt = 0; mt < 4; mt++)
#pragma unroll
        for (int nt = 0; nt < 4; nt++) {
            const int col = n0 + wn + nt*16 + (lane & 15);
            const float bcol = bias[col];
#pragma unroll
            for (int rg = 0; rg < 4; rg++) {
                const int row = m0 + wm + mt*16 + (lane >> 4)*4 + rg;
                C[(i64)row * CH + col] = acc[mt][nt][rg] + bcol;
            }
        }
}

__global__ __launch_bounds__(256)
void cast_w(const float* __restrict__ src, unsigned short* __restrict__ dst, int n4)
{
    int i = blockIdx.x * 256 + threadIdx.x;
    if (i >= n4) return;
    float4 v = *(const float4*)&src[i*4];
    unsigned short o[4];
    o[0] = __bfloat16_as_ushort(__float2bfloat16(v.x));
    o[1] = __bfloat16_as_ushort(__float2bfloat16(v.y));
    o[2] = __bfloat16_as_ushort(__float2bfloat16(v.z));
    o[3] = __bfloat16_as_ushort(__float2bfloat16(v.w));
    *(uint2*)&dst[i*4] = *(uint2*)o;
}

// ---------------- top-k select (unchanged logic; ctx stored as bf16) -------
__device__ __forceinline__ float wave_fsum(float v) {
#pragma unroll
    for (int m = 32; m; m >>= 1) v += __shfl_xor(v, m, 64);
    return v;
}
__device__ __forceinline__ int wave_isum(int v) {
#pragma unroll
    for (int m = 32; m; m >>= 1) v += __shfl_xor(v, m, 64);
    return v;
}
__device__ __forceinline__ unsigned fkey(float t) {
    unsigned bits = __float_as_uint(t);
    return (bits & 0x80000000u) ? ~bits : (bits | 0x80000000u);
}

__global__ __launch_bounds__(256)
void select_topk(const float* __restrict__ scores, i64 sstride,
                 const float* __restrict__ ucb_cnt,
                 const float* __restrict__ qkv,
                 unsigned short* __restrict__ ctxbf,
                 float* __restrict__ sdelta,
                 const int* __restrict__ counter_p,
                 int b0, int b1)
{
    __shared__ __align__(16) float    s_vals[SEQ];
    __shared__ __align__(16) unsigned u_vals[SEQ];
    __shared__ __align__(4)  unsigned char selflag[SEQ];
    __shared__ unsigned hist[256];
    __shared__ unsigned wtot[4];
    __shared__ float    fred[4];
    __shared__ int      ired[4];
    __shared__ float    cred[256];
    __shared__ float    wsel[128];
    __shared__ int      isel[128];
    __shared__ unsigned sh_prefix;
    __shared__ int      sh_r, sh_cnt;

    const int tid = threadIdx.x;
    const int lane = tid & 63, wid = tid >> 6;
    const int n = blockIdx.x, h = blockIdx.y;
    const float L = logf((float)(*counter_p));
    const i64 rowoff = ((i64)h * SEQ + n) * SEQ;
    const bool owner = tid < NE4;

    float4 bon = make_float4(0.f,0.f,0.f,0.f);
    if (owner) {
        float4 c4 = *(const float4*)&ucb_cnt[rowoff + tid*4];
        bon.x = sqrtf(L / (c4.x + 1e-6f));
        bon.y = sqrtf(L / (c4.y + 1e-6f));
        bon.z = sqrtf(L / (c4.z + 1e-6f));
        bon.w = sqrtf(L / (c4.w + 1e-6f));
    }
    int cnt_acc[4] = {0,0,0,0};
    hist[tid] = 0u;

    for (int b = b0; b < b1; b++) {
        const float* srow = scores + (i64)(b - b0) * sstride + rowoff;
        if (tid == 0) { sh_prefix = 0u; sh_r = K_TOP; sh_cnt = 0; }
        if (owner) {
            float4 s4 = *(const float4*)&srow[tid*4];
            *(float4*)&s_vals[tid*4] = s4;
            uint4 uu;
            uu.x = fkey(s4.x + bon.x);
            uu.y = fkey(s4.y + bon.y);
            uu.z = fkey(s4.z + bon.z);
            uu.w = fkey(s4.w + bon.w);
            *(uint4*)&u_vals[tid*4] = uu;
            *(uchar4*)&selflag[tid*4] = make_uchar4(0,0,0,0);
        }
        __syncthreads();

        unsigned prefix = 0u; int r = K_TOP;
#pragma unroll
        for (int pass = 3; pass >= 0; pass--) {
            const int shift = pass * 8;
            const unsigned mask_hi = (pass == 3) ? 0u : (0xFFFFFFFFu << (shift + 8));
            if (owner) {
#pragma unroll
                for (int j = 0; j < 4; j++) {
                    unsigned u = u_vals[tid*4 + j];
                    if ((u & mask_hi) == prefix)
                        atomicAdd(&hist[(u >> shift) & 255u], 1u);
                }
            }
            __syncthreads();
            const unsigned hme = hist[tid];
            unsigned ssum = hme;
#pragma unroll
            for (int off = 1; off < 64; off <<= 1) {
                unsigned t = __shfl_down(ssum, off, 64);
                if (lane + off < 64) ssum += t;
            }
            if (lane == 0) wtot[wid] = ssum;
            __syncthreads();
            unsigned above = 0;
            for (int ww = wid + 1; ww < 4; ww++) above += wtot[ww];
            const unsigned cge = ssum + above;
            const unsigned cgt = cge - hme;
            if ((int)cge >= r && (int)cgt < r) {
                sh_prefix = prefix | ((unsigned)tid << shift);
                sh_r = r - (int)cgt;
            }
            hist[tid] = 0u;
            __syncthreads();
            prefix = sh_prefix; r = sh_r;
        }
        const unsigned T = prefix;
        const int rfin = r;

        int myeq = 0;
        if (owner) {
#pragma unroll
            for (int j = 0; j < 4; j++) {
                unsigned u = u_vals[tid*4 + j];
                if (u > T) selflag[tid*4 + j] = 1;
                myeq += (u == T);
            }
        }
        int weq = wave_isum(myeq);
        if (lane == 0) ired[wid] = weq;
        __syncthreads();
        const int ceq = ired[0] + ired[1] + ired[2] + ired[3];
        if (ceq == rfin) {
            if (owner) {
#pragma unroll
                for (int j = 0; j < 4; j++)
                    if (u_vals[tid*4 + j] == T) selflag[tid*4 + j] = 1;
            }
        } else if (tid == 0) {
            int nd = rfin;
            for (int m = 0; m < SEQ && nd > 0; m++)
                if (u_vals[m] == T) { selflag[m] = 1; nd--; }
        }
        __syncthreads();

        float pw = 0.f;
        if (owner) {
#pragma unroll
            for (int j = 0; j < 4; j++) {
                if (selflag[tid*4 + j]) {
                    int pos = atomicAdd(&sh_cnt, 1);
                    if (pos < 128) { isel[pos] = tid*4 + j; wsel[pos] = s_vals[tid*4 + j]; }
                    pw += s_vals[tid*4 + j];
                    cnt_acc[j]++;
                }
            }
        }
        float w0 = wave_fsum(pw);
        if (lane == 0) fred[wid] = w0;
        __syncthreads();
        const float inv = 1.0f / (fred[0] + fred[1] + fred[2] + fred[3] + 1e-8f);
        const int cnt = (sh_cnt < 128) ? sh_cnt : 128;

        const int d = tid & 63, g = tid >> 6;
        float acc = 0.f;
        const float* vbase = qkv + (i64)b * SEQ * (3*CH) + 2*CH + h * DH + d;
        for (int j = g; j < cnt; j += 4)
            acc += wsel[j] * vbase[(i64)isel[j] * (3*CH)];
        cred[tid] = acc;
        __syncthreads();
        if (tid < 64) {
            float tot = cred[tid] + cred[tid+64] + cred[tid+128] + cred[tid+192];
            ctxbf[((i64)b * SEQ + n) * CH + h * DH + tid] =
                __bfloat16_as_ushort(__float2bfloat16(inv * tot));
        }
        __syncthreads();
    }

    if (owner) {
        float4 o;
        o.x = (float)cnt_acc[0]; o.y = (float)cnt_acc[1];
        o.z = (float)cnt_acc[2]; o.w = (float)cnt_acc[3];
        float* dst = &sdelta[rowoff + tid*4];
        if (b0 != 0) {
            float4 p = *(const float4*)dst;
            o.x += p.x; o.y += p.y; o.z += p.z; o.w += p.w;
        }
        *(float4*)dst = o;
    }
}

extern "C" void kernel_launch(void* const* d_in, const int* in_sizes, int n_in,
                              void* d_out, int out_size, void* d_ws, size_t ws_size,
                              hipStream_t stream) {
    const float* x      = (const float*)d_in[0];
    const float* ucb    = (const float*)d_in[1];
    const float* qkv_w  = (const float*)d_in[2];
    const float* proj_w = (const float*)d_in[3];
    const float* proj_b = (const float*)d_in[4];
    const int*   counter = (const int*)d_in[5];

    float* out0   = (float*)d_out;
    float* sdelta = out0 + (i64)NB * SEQ * CH;

    const size_t qkv_f  = (size_t)NB * SEQ * (3*CH);          // fp32
    const size_t ctx_h  = (size_t)NB * SEQ * CH;              // bf16 (ushort)
    const size_t w_h    = (size_t)CH * CH;                    // bf16
    const size_t sc1_f  = (size_t)NH * SEQ * SEQ;

    float* qkv_buf = (float*)d_ws;
    unsigned short* ctx_bf = (unsigned short*)(qkv_buf + qkv_f);
    unsigned short* w_bf   = ctx_bf + ctx_h;
    // align scores to 16B
    size_t off = ((qkv_f * 4 + (ctx_h + w_h) * 2) + 15) & ~(size_t)15;
    float* scores = (float*)((char*)d_ws + off);
    const bool merged = ws_size >= off + (size_t)NB * sc1_f * 4;

    dim3 blk(256);

    cast_w<<<dim3((CH*CH/4 + 255)/256), blk, 0, stream>>>(proj_w, w_bf, CH*CH/4);

    gemm_qkv<<<dim3(18, 49), blk, 0, stream>>>(x, qkv_w, qkv_buf);

    if (merged) {
        gemm_scores<<<dim3(7, 7, NB*NH), blk, 0, stream>>>(
            qkv_buf, scores, 0, (i64)SEQ*SEQ);
        select_topk<<<dim3(SEQ, NH), blk, 0, stream>>>(
            scores, (i64)NH*SEQ*SEQ, ucb, qkv_buf, ctx_bf, sdelta, counter, 0, NB);
    } else {
        for (int b = 0; b < NB; b++) {
            gemm_scores<<<dim3(7, 7, NH), blk, 0, stream>>>(
                qkv_buf, scores, b, (i64)SEQ*SEQ);
            select_topk<<<dim3(SEQ, NH), blk, 0, stream>>>(
                scores, 0, ucb, qkv_buf, ctx_bf, sdelta, counter, b, b + 1);
        }
    }

    gemm_proj<<<dim3(6, 49), blk, 0, stream>>>(ctx_bf, w_bf, proj_b, out0);
}